// Round 10
// baseline (400.640 us; speedup 1.0000x reference)
//
#include <hip/hip_runtime.h>
#include <hip/hip_bf16.h>
#include <hip/hip_fp16.h>

#define N_NODES 100000
#define N_PAD 100032            // 64-row multiple for GEMM staging
#define N_EDGES 1600000
#define N_GRAPHS 512
#define HID 192
#define EPSV 1e-5f

using f16x8 = __attribute__((ext_vector_type(8))) _Float16;
using f16x4 = __attribute__((ext_vector_type(4))) _Float16;
using f32x4 = __attribute__((ext_vector_type(4))) float;

// ---------------- CSR build ----------------
__global__ void k_count(const int* __restrict__ col, int* __restrict__ cnt) {
    int e = blockIdx.x * blockDim.x + threadIdx.x;
    if (e < N_EDGES) atomicAdd(&cnt[col[e]], 1);
}

// merged small prep: W2->fp16 + gstart binary search
__global__ void k_misc(const float* __restrict__ W2, _Float16* __restrict__ W2h,
                       const int* __restrict__ batch, int* __restrict__ gstart) {
    int id = blockIdx.x * blockDim.x + threadIdx.x;
    if (id < HID * HID) W2h[id] = (_Float16)W2[id];
    int g = id - HID * HID;
    if (g >= 0 && g <= N_GRAPHS) {
        if (g == N_GRAPHS) { gstart[g] = N_NODES; return; }
        int lo = 0, hi = N_NODES;
        while (lo < hi) { int mid = (lo + hi) >> 1; if (batch[mid] < g) lo = mid + 1; else hi = mid; }
        gstart[g] = lo;
    }
}

__global__ void k_scan_partial(const int* __restrict__ cnt, int* __restrict__ bsum) {
    __shared__ int sd[256];
    int base = blockIdx.x * 1024;
    int t = threadIdx.x;
    int s = 0;
    for (int j = 0; j < 4; ++j) {
        int i = base + j * 256 + t;
        if (i < N_NODES) s += cnt[i];
    }
    sd[t] = s; __syncthreads();
    for (int off = 128; off > 0; off >>= 1) {
        if (t < off) sd[t] += sd[t + off];
        __syncthreads();
    }
    if (t == 0) bsum[blockIdx.x] = sd[0];
}

// scan_final: block offset from raw bsum partials; initializes interleaved
// [cursor, acc] pairs (same cache line -> fill's two atomics share a line).
__global__ void k_scan_final(const int* __restrict__ cnt, const int* __restrict__ bsum,
                             int nb, int* __restrict__ row_ptr, int* __restrict__ cur_acc,
                             float* __restrict__ dinv, const float* __restrict__ x,
                             float* __restrict__ xp) {
    __shared__ int sd[256];
    __shared__ int s_off;
    int bid = blockIdx.x;
    int t = threadIdx.x;
    int part = 0;
    for (int i = t; i < bid; i += 256) part += bsum[i];
    sd[t] = part; __syncthreads();
    for (int off = 128; off > 0; off >>= 1) {
        if (t < off) sd[t] += sd[t + off];
        __syncthreads();
    }
    if (t == 0) s_off = sd[0];
    __syncthreads();
    int base = bid * 1024;
    int idx0 = base + t * 4;
    int c[4]; int tot = 0;
    for (int j = 0; j < 4; ++j) {
        int i = idx0 + j;
        c[j] = (i < N_NODES) ? cnt[i] : 0;
        tot += c[j];
    }
    sd[t] = tot; __syncthreads();
    for (int off = 1; off < 256; off <<= 1) {
        int v = (t >= off) ? sd[t - off] : 0;
        __syncthreads();
        sd[t] += v;
        __syncthreads();
    }
    int excl = sd[t] - tot + s_off;
    for (int j = 0; j < 4; ++j) {
        int i = idx0 + j;
        if (i < N_NODES) {
            row_ptr[i] = excl;
            cur_acc[2 * i] = excl;
            cur_acc[2 * i + 1] = 0;          // float 0.0 bits
            float dv = rsqrtf((float)(c[j] + 1));   // deg = in-degree + self-loop
            dinv[i] = dv;
            xp[i] = x[i] * dv;
            excl += c[j];
        }
    }
    if (bid == nb - 1 && t == 255) row_ptr[N_NODES] = excl;
}

// XCD-bound windowed fill + fused layer-1 edge-sum: block b scatters ONLY
// dest-window (b&7) over edge slice (b>>3); cursor and acc atomics share a
// cache line (interleaved pairs), all window-local in one XCD's L2.
#define FILL_WIN 8
#define FILL_RANGE (N_NODES / FILL_WIN)     // 12500
#define EPR ((N_EDGES + 255) / 256)         // 6250 edges per rank
__global__ void __launch_bounds__(256) k_fill(const int* __restrict__ row,
                                              const int* __restrict__ col,
                                              const float* __restrict__ xp,
                                              int* __restrict__ cur_acc,
                                              int* __restrict__ csr_src) {
    int w = blockIdx.x & 7;
    int rank = blockIdx.x >> 3;             // 0..255
    int lo = w * FILL_RANGE;
    int hi = (w == FILL_WIN - 1) ? N_NODES : lo + FILL_RANGE;
    int e0 = rank * EPR;
    int e1 = min(e0 + EPR, N_EDGES);
    for (int e = e0 + threadIdx.x; e < e1; e += 256) {
        int c = col[e];
        if (c >= lo && c < hi) {
            int r = row[e];
            int pos = atomicAdd(&cur_acc[2 * c], 1);
            atomicAdd((float*)&cur_acc[2 * c + 1], xp[r]);
            csr_src[pos] = r;
        }
    }
}

// ------------- per-graph scalar stats + A/B tables (u recomputed from acc) -------------
// relu(graphnorm1(h1))[i,f] = relu(A[g,f]*u_i + B[g,f]); u_i = dv*(acc_i + x_i*dv)
__global__ void __launch_bounds__(192) k_stats_ab(const int* __restrict__ cur_acc,
                                                  const float* __restrict__ x,
                                                  const float* __restrict__ dinv,
                                                  const int* __restrict__ gstart,
                                                  const float* __restrict__ W1, const float* __restrict__ b1,
                                                  const float* __restrict__ g1, const float* __restrict__ be1,
                                                  const float* __restrict__ a1,
                                                  float* __restrict__ A, float* __restrict__ B) {
    __shared__ float sd[192], sd2[192];
    int g = blockIdx.x, t = threadIdx.x;
    int i0 = gstart[g], i1 = gstart[g + 1];
    const float* ca = (const float*)cur_acc;
    float s = 0.f, s2 = 0.f;
    for (int i = i0 + t; i < i1; i += 192) {
        float dv = dinv[i];
        float u = dv * (ca[2 * i + 1] + x[i] * dv);
        s += u; s2 += u * u;
    }
    sd[t] = s; sd2[t] = s2; __syncthreads();
    for (int off = 96; off >= 3; off >>= 1) {
        if (t < off) { sd[t] += sd[t + off]; sd2[t] += sd2[t + off]; }
        __syncthreads();
    }
    float sum_u = sd[0] + sd[1] + sd[2];
    float sum_u2 = sd2[0] + sd2[1] + sd2[2];
    float cntf = fmaxf((float)(i1 - i0), 1.f);
    float m = sum_u / cntf;
    float es2 = sum_u2 / cntf;
    int f = t;
    float w = W1[f], bb = b1[f], al = a1[f];
    float c2 = bb * (1.f - al);
    float d = al * m;
    float eud2 = es2 - 2.f * d * m + d * d;          // E[(u-d)^2]
    float var = w * w * eud2 + 2.f * w * c2 * (m - d) + c2 * c2;
    float rs = rsqrtf(var + EPSV);
    float gam = g1[f];
    A[g * HID + f] = gam * rs * w;
    B[g * HID + f] = gam * rs * (c2 - w * d) + be1[f];
}

// ------------- X1p[v,f] = fp16( relu(A[gv,f]*u_v + B[gv,f]) * dinv_v ) -------------
__global__ void __launch_bounds__(256) k_x1(const int* __restrict__ cur_acc,
                                            const float* __restrict__ x,
                                            const float* __restrict__ dinv,
                                            const int* __restrict__ batch,
                                            const float* __restrict__ A,
                                            const float* __restrict__ B,
                                            _Float16* __restrict__ X1p) {
    int wid = threadIdx.x >> 6;
    int lane = threadIdx.x & 63;
    int v = blockIdx.x * 4 + wid;
    if (v >= N_NODES) return;
    float dv = dinv[v];
    float u = dv * (((const float*)cur_acc)[2 * v + 1] + x[v] * dv);
    int g = batch[v];
    int c4 = (lane < 48 ? lane : 47) * 4;
    float4 Av = *(const float4*)(A + g * HID + c4);
    float4 Bv = *(const float4*)(B + g * HID + c4);
    f16x4 o;
    o[0] = (_Float16)(fmaxf(fmaf(Av.x, u, Bv.x), 0.f) * dv);
    o[1] = (_Float16)(fmaxf(fmaf(Av.y, u, Bv.y), 0.f) * dv);
    o[2] = (_Float16)(fmaxf(fmaf(Av.z, u, Bv.z), 0.f) * dv);
    o[3] = (_Float16)(fmaxf(fmaf(Av.w, u, Bv.w), 0.f) * dv);
    if (lane < 48) *(f16x4*)(X1p + (size_t)v * HID + c4) = o;
}

// ------------- layer 2 aggregation: aggh[v,:] = fp16( dv * (X1p[v] + sum_nbr X1p[s]) ) ----
#define CH 8
__global__ void __launch_bounds__(256) k_conv2(const _Float16* __restrict__ X1p,
                                               const float* __restrict__ dinv,
                                               const int* __restrict__ row_ptr,
                                               const int* __restrict__ csr_src,
                                               _Float16* __restrict__ aggh) {
    int wid = threadIdx.x >> 6;
    int lane = threadIdx.x & 63;
    int v = blockIdx.x * 4 + wid;
    if (v >= N_NODES) return;
    unsigned c8 = (unsigned)(lane < 48 ? lane : 47) * 8u;
    const char* Xb = (const char*)X1p;
    float dv = dinv[v];
    f16x4 sv = *(const f16x4*)(Xb + (unsigned)v * (HID * 2) + c8);
    float a0 = (float)sv[0], a1 = (float)sv[1], a2 = (float)sv[2], a3 = (float)sv[3];
    int e0 = row_ptr[v], e1 = row_ptr[v + 1];
    for (int b = e0; b < e1; b += CH) {
        unsigned off[CH]; float wgt[CH];
#pragma unroll
        for (int j = 0; j < CH; ++j) {
            int e = b + j;
            off[j] = (unsigned)csr_src[(e < e1) ? e : e0] * (unsigned)(HID * 2) + c8;
            wgt[j] = (e < e1) ? 1.f : 0.f;
        }
        f16x4 rv[CH];
#pragma unroll
        for (int j = 0; j < CH; ++j)
            rv[j] = *(const f16x4*)(Xb + off[j]);
#pragma unroll
        for (int j = 0; j < CH; ++j) {
            a0 = fmaf(wgt[j], (float)rv[j][0], a0);
            a1 = fmaf(wgt[j], (float)rv[j][1], a1);
            a2 = fmaf(wgt[j], (float)rv[j][2], a2);
            a3 = fmaf(wgt[j], (float)rv[j][3], a3);
        }
    }
    if (lane < 48) {
        f16x4 o;
        o[0] = (_Float16)(a0 * dv);
        o[1] = (_Float16)(a1 * dv);
        o[2] = (_Float16)(a2 * dv);
        o[3] = (_Float16)(a3 * dv);
        *(f16x4*)((char*)aggh + (unsigned)v * (HID * 2) + c8) = o;
    }
}

// ------------- MFMA GEMM + fused graphnorm2 stats -------------
// h2 = aggh @ W2h + b2; per-block segment-reduced sum/sumsq atomics (values
// already in registers; 64-row tile spans <=2 graphs since min graph >> 64).
#define BM 64
__global__ void __launch_bounds__(256) k_gemm(const _Float16* __restrict__ A,
                                              const _Float16* __restrict__ W,
                                              const float* __restrict__ b2,
                                              const int* __restrict__ batch,
                                              _Float16* __restrict__ H,
                                              float* __restrict__ sums,
                                              float* __restrict__ sumsq) {
    __shared__ _Float16 a_lds[BM * HID];   // 24 KB
    __shared__ int bb[BM];
    int t = threadIdx.x;
    int wid = t >> 6, lane = t & 63;
    int row0 = blockIdx.x * BM;
    if (t < BM) { int gr = row0 + t; bb[t] = (gr < N_NODES) ? batch[gr] : -1; }
    const char* Ablk = (const char*)(A + (size_t)row0 * HID);
#pragma unroll
    for (int it = 0; it < 6; ++it) {
        int bo = (it * 256 + t) * 16;
        int r = bo / 384;
        int swz = bo ^ ((r & 7) << 4);
        *(float4*)((char*)a_lds + swz) = *(const float4*)(Ablk + bo);
    }
    int n0 = wid * 48;
    int bn = n0 + (lane & 15);
    int bk0 = (lane >> 4) << 3;            // k group base (0,8,16,24)
    f16x8 bfr[6][3];
#pragma unroll
    for (int kc = 0; kc < 6; ++kc)
#pragma unroll
        for (int nt = 0; nt < 3; ++nt) {
            const _Float16* src = W + (size_t)(kc * 32 + bk0) * HID + bn + nt * 16;
            f16x8 v;
#pragma unroll
            for (int j = 0; j < 8; ++j) v[j] = src[(size_t)j * HID];
            bfr[kc][nt] = v;
        }
    __syncthreads();
    f32x4 acc[4][3];
#pragma unroll
    for (int mt = 0; mt < 4; ++mt)
#pragma unroll
        for (int nt = 0; nt < 3; ++nt) acc[mt][nt] = (f32x4){0.f, 0.f, 0.f, 0.f};
    int ar = lane & 15;
#pragma unroll
    for (int mt = 0; mt < 4; ++mt) {
        int r = mt * 16 + ar;
        int rbase = r * 384;
        int sw = (r & 7) << 4;
#pragma unroll
        for (int kc = 0; kc < 6; ++kc) {
            int bo = (rbase + (kc * 32 + bk0) * 2) ^ sw;
            f16x8 a = *(const f16x8*)((const char*)a_lds + bo);
            acc[mt][0] = __builtin_amdgcn_mfma_f32_16x16x32_f16(a, bfr[kc][0], acc[mt][0], 0, 0, 0);
            acc[mt][1] = __builtin_amdgcn_mfma_f32_16x16x32_f16(a, bfr[kc][1], acc[mt][1], 0, 0, 0);
            acc[mt][2] = __builtin_amdgcn_mfma_f32_16x16x32_f16(a, bfr[kc][2], acc[mt][2], 0, 0, 0);
        }
    }
    // epilogue: bias + fp16 store + segment stats (D: col=lane&15, row=(lane>>4)*4+reg)
    int cn = lane & 15;
    int rb = (lane >> 4) * 4;
    float bias[3];
#pragma unroll
    for (int nt = 0; nt < 3; ++nt) bias[nt] = b2[n0 + nt * 16 + cn];
    int gA = bb[0];
    int lastv = min(BM, N_NODES - row0) - 1;
    int gB = bb[lastv];
    float sA[3] = {0.f,0.f,0.f}, qA[3] = {0.f,0.f,0.f};
    float sB[3] = {0.f,0.f,0.f}, qB[3] = {0.f,0.f,0.f};
#pragma unroll
    for (int mt = 0; mt < 4; ++mt)
#pragma unroll
        for (int r = 0; r < 4; ++r) {
            int ridx = mt * 16 + rb + r;
            int grow = row0 + ridx;
            if (grow < N_NODES) {
                int gi = bb[ridx];
                _Float16* o = H + (size_t)grow * HID;
#pragma unroll
                for (int nt = 0; nt < 3; ++nt) {
                    float val = acc[mt][nt][r] + bias[nt];
                    o[n0 + nt * 16 + cn] = (_Float16)val;
                    if (gi == gA) { sA[nt] += val; qA[nt] += val * val; }
                    else          { sB[nt] += val; qB[nt] += val * val; }
                }
            }
        }
    // column-reduce across the 4 lane groups (rows) sharing each col
#pragma unroll
    for (int nt = 0; nt < 3; ++nt) {
        sA[nt] += __shfl_xor(sA[nt], 16); sA[nt] += __shfl_xor(sA[nt], 32);
        qA[nt] += __shfl_xor(qA[nt], 16); qA[nt] += __shfl_xor(qA[nt], 32);
        sB[nt] += __shfl_xor(sB[nt], 16); sB[nt] += __shfl_xor(sB[nt], 32);
        qB[nt] += __shfl_xor(qB[nt], 16); qB[nt] += __shfl_xor(qB[nt], 32);
    }
    if (lane < 16) {
#pragma unroll
        for (int nt = 0; nt < 3; ++nt) {
            int colf = n0 + nt * 16 + cn;
            atomicAdd(&sums[gA * HID + colf], sA[nt]);
            atomicAdd(&sumsq[gA * HID + colf], qA[nt]);
            if (gB != gA) {
                atomicAdd(&sums[gB * HID + colf], sB[nt]);
                atomicAdd(&sumsq[gB * HID + colf], qB[nt]);
            }
        }
    }
}

// ------------- pool: relu(C*h+D) per graph with inline C/D (atomics) -------------
__global__ void __launch_bounds__(192) k_pool(const _Float16* __restrict__ h,
                                              const int* __restrict__ batch,
                                              const int* __restrict__ gstart,
                                              const float* __restrict__ sums,
                                              const float* __restrict__ sumsq,
                                              const float* __restrict__ g2,
                                              const float* __restrict__ be2,
                                              const float* __restrict__ a2,
                                              float* __restrict__ pooled) {
    int f = threadIdx.x;
    int r0 = blockIdx.x * 64;
    int r1 = min(r0 + 64, N_NODES);
    float al = a2[f], gam = g2[f], bet = be2[f];
    int g = batch[r0];
    float Cg, Dg;
    auto cd = [&](int gg) {
        float cntf = fmaxf((float)(gstart[gg + 1] - gstart[gg]), 1.f);
        float mh = sums[gg * HID + f] / cntf;
        float msq = sumsq[gg * HID + f] / cntf;
        float var = msq - 2.f * al * mh * mh + al * al * mh * mh;
        Cg = gam * rsqrtf(var + EPSV);
        Dg = bet - Cg * al * mh;
    };
    cd(g);
    float s = 0.f;
    int i = r0;
    for (; i + 4 <= r1; i += 4) {
        int g0 = batch[i], g3 = batch[i + 3];
        float v0 = (float)h[(size_t)(i + 0) * HID + f];
        float v1 = (float)h[(size_t)(i + 1) * HID + f];
        float v2 = (float)h[(size_t)(i + 2) * HID + f];
        float v3 = (float)h[(size_t)(i + 3) * HID + f];
        if (g0 == g && g3 == g) {
            s += fmaxf(fmaf(Cg, v0, Dg), 0.f) + fmaxf(fmaf(Cg, v1, Dg), 0.f);
            s += fmaxf(fmaf(Cg, v2, Dg), 0.f) + fmaxf(fmaf(Cg, v3, Dg), 0.f);
        } else {
            float vv[4] = {v0, v1, v2, v3};
            for (int j = 0; j < 4; ++j) {
                int gi = batch[i + j];
                if (gi != g) {
                    atomicAdd(&pooled[g * HID + f], s);
                    s = 0.f; g = gi; cd(g);
                }
                s += fmaxf(fmaf(Cg, vv[j], Dg), 0.f);
            }
        }
    }
    for (; i < r1; ++i) {
        int gi = batch[i];
        float v = (float)h[(size_t)i * HID + f];
        if (gi != g) {
            atomicAdd(&pooled[g * HID + f], s);
            s = 0.f; g = gi; cd(g);
        }
        s += fmaxf(fmaf(Cg, v, Dg), 0.f);
    }
    atomicAdd(&pooled[g * HID + f], s);
}

// ------------- final MLP: out = relu((pooled/cnt)@Wc1+bc1)@Wc2 + bc2 -------------
__global__ void __launch_bounds__(128) k_mlp(const float* __restrict__ pooled,
                                             const int* __restrict__ gstart,
                                             const float* __restrict__ Wc1,
                                             const float* __restrict__ bc1,
                                             const float* __restrict__ Wc2,
                                             const float* __restrict__ bc2,
                                             float* __restrict__ out) {
    __shared__ float p[HID];
    __shared__ float z[96];
    int g = blockIdx.x, t = threadIdx.x;
    float inv = 1.f / fmaxf((float)(gstart[g + 1] - gstart[g]), 1.f);
    for (int i = t; i < HID; i += 128) p[i] = pooled[g * HID + i] * inv;
    __syncthreads();
    if (t < 96) {
        float acc = bc1[t];
        for (int k = 0; k < HID; ++k) acc += p[k] * Wc1[k * 96 + t];
        z[t] = fmaxf(acc, 0.f);
    }
    __syncthreads();
    if (t < 4) {
        float acc = bc2[t];
        for (int j = 0; j < 96; ++j) acc += z[j] * Wc2[j * 4 + t];
        out[g * 4 + t] = acc;
    }
}

extern "C" void kernel_launch(void* const* d_in, const int* in_sizes, int n_in,
                              void* d_out, int out_size, void* d_ws, size_t ws_size,
                              hipStream_t stream) {
    const float* x   = (const float*)d_in[0];
    const int* eidx  = (const int*)d_in[1];
    const int* batch = (const int*)d_in[2];
    const float* W1  = (const float*)d_in[3];
    const float* b1  = (const float*)d_in[4];
    const float* g1  = (const float*)d_in[5];
    const float* be1 = (const float*)d_in[6];
    const float* a1  = (const float*)d_in[7];
    const float* W2  = (const float*)d_in[8];
    const float* b2  = (const float*)d_in[9];
    const float* g2  = (const float*)d_in[10];
    const float* be2 = (const float*)d_in[11];
    const float* a2  = (const float*)d_in[12];
    const float* Wc1 = (const float*)d_in[13];
    const float* bc1 = (const float*)d_in[14];
    const float* Wc2 = (const float*)d_in[15];
    const float* bc2 = (const float*)d_in[16];
    const int* row = eidx;
    const int* col = eidx + N_EDGES;
    float* out = (float*)d_out;

    char* ws = (char*)d_ws;
    size_t off = 0;
    auto alloc = [&](size_t bytes) -> char* {
        char* p = ws + off;
        off = (off + bytes + 255) & ~(size_t)255;
        return p;
    };
    // ---- zero region (contiguous) ----
    int*   cnt     = (int*)  alloc(N_NODES * 4);
    float* sums2   = (float*)alloc(N_GRAPHS * HID * 4);
    float* sumsq2  = (float*)alloc(N_GRAPHS * HID * 4);
    float* pooled  = (float*)alloc(N_GRAPHS * HID * 4);
    size_t zbytes  = off;
    // ---- rest ----
    int*   bsum    = (int*)  alloc(128 * 4);
    int*   row_ptr = (int*)  alloc((N_NODES + 1) * 4);
    int*   cur_acc = (int*)  alloc((size_t)N_NODES * 8);   // interleaved [cursor, accbits]
    int*   csr_src = (int*)  alloc(N_EDGES * 4);
    float* dinv    = (float*)alloc(N_NODES * 4);
    float* xp      = (float*)alloc(N_NODES * 4);
    float* Atab    = (float*)alloc(N_GRAPHS * HID * 4);
    float* Btab    = (float*)alloc(N_GRAPHS * HID * 4);
    int*   gstart  = (int*)  alloc((N_GRAPHS + 1) * 4);
    _Float16* X1p  = (_Float16*)alloc((size_t)N_NODES * HID * 2);
    _Float16* aggh = (_Float16*)alloc((size_t)N_PAD * HID * 2);
    _Float16* h2   = (_Float16*)alloc((size_t)N_NODES * HID * 2);
    _Float16* W2h  = (_Float16*)alloc((size_t)HID * HID * 2);

    hipMemsetAsync(ws, 0, zbytes, stream);
    k_misc<<<(HID * HID + N_GRAPHS + 1 + 255) / 256, 256, 0, stream>>>(W2, W2h, batch, gstart);
    k_count<<<(N_EDGES + 255) / 256, 256, 0, stream>>>(col, cnt);
    int PB = (N_NODES + 1023) / 1024;
    k_scan_partial<<<PB, 256, 0, stream>>>(cnt, bsum);
    k_scan_final<<<PB, 256, 0, stream>>>(cnt, bsum, PB, row_ptr, cur_acc, dinv, x, xp);
    k_fill<<<2048, 256, 0, stream>>>(row, col, xp, cur_acc, csr_src);
    k_stats_ab<<<N_GRAPHS, 192, 0, stream>>>(cur_acc, x, dinv, gstart, W1, b1, g1, be1, a1, Atab, Btab);
    k_x1<<<(N_NODES + 3) / 4, 256, 0, stream>>>(cur_acc, x, dinv, batch, Atab, Btab, X1p);
    k_conv2<<<(N_NODES + 3) / 4, 256, 0, stream>>>(X1p, dinv, row_ptr, csr_src, aggh);
    k_gemm<<<(N_NODES + BM - 1) / BM, 256, 0, stream>>>(aggh, W2h, b2, batch, h2, sums2, sumsq2);
    int SB = (N_NODES + 63) / 64;
    k_pool<<<SB, 192, 0, stream>>>(h2, batch, gstart, sums2, sumsq2, g2, be2, a2, pooled);
    k_mlp<<<N_GRAPHS, 128, 0, stream>>>(pooled, gstart, Wc1, bc1, Wc2, bc2, out);
}

// Round 11
// 335.267 us; speedup vs baseline: 1.1950x; 1.1950x over previous
//
#include <hip/hip_runtime.h>
#include <hip/hip_bf16.h>
#include <hip/hip_fp16.h>

#define N_NODES 100000
#define N_PAD 100032            // 64-row multiple for GEMM staging
#define N_EDGES 1600000
#define N_GRAPHS 512
#define HID 192
#define EPSV 1e-5f

using f16x8 = __attribute__((ext_vector_type(8))) _Float16;
using f16x4 = __attribute__((ext_vector_type(4))) _Float16;
using f32x4 = __attribute__((ext_vector_type(4))) float;

// ---------------- CSR build ----------------
__global__ void k_count(const int* __restrict__ col, int* __restrict__ cnt) {
    int e = blockIdx.x * blockDim.x + threadIdx.x;
    if (e < N_EDGES) atomicAdd(&cnt[col[e]], 1);
}

// merged small prep: W2->fp16 + gstart binary search
__global__ void k_misc(const float* __restrict__ W2, _Float16* __restrict__ W2h,
                       const int* __restrict__ batch, int* __restrict__ gstart) {
    int id = blockIdx.x * blockDim.x + threadIdx.x;
    if (id < HID * HID) W2h[id] = (_Float16)W2[id];
    int g = id - HID * HID;
    if (g >= 0 && g <= N_GRAPHS) {
        if (g == N_GRAPHS) { gstart[g] = N_NODES; return; }
        int lo = 0, hi = N_NODES;
        while (lo < hi) { int mid = (lo + hi) >> 1; if (batch[mid] < g) lo = mid + 1; else hi = mid; }
        gstart[g] = lo;
    }
}

__global__ void k_scan_partial(const int* __restrict__ cnt, int* __restrict__ bsum) {
    __shared__ int sd[256];
    int base = blockIdx.x * 1024;
    int t = threadIdx.x;
    int s = 0;
    for (int j = 0; j < 4; ++j) {
        int i = base + j * 256 + t;
        if (i < N_NODES) s += cnt[i];
    }
    sd[t] = s; __syncthreads();
    for (int off = 128; off > 0; off >>= 1) {
        if (t < off) sd[t] += sd[t + off];
        __syncthreads();
    }
    if (t == 0) bsum[blockIdx.x] = sd[0];
}

// scan_final computes its own block offset from raw bsum partials.
__global__ void k_scan_final(const int* __restrict__ cnt, const int* __restrict__ bsum,
                             int nb, int* __restrict__ row_ptr, int* __restrict__ cursor,
                             float* __restrict__ dinv, const float* __restrict__ x,
                             float* __restrict__ xp) {
    __shared__ int sd[256];
    __shared__ int s_off;
    int bid = blockIdx.x;
    int t = threadIdx.x;
    int part = 0;
    for (int i = t; i < bid; i += 256) part += bsum[i];
    sd[t] = part; __syncthreads();
    for (int off = 128; off > 0; off >>= 1) {
        if (t < off) sd[t] += sd[t + off];
        __syncthreads();
    }
    if (t == 0) s_off = sd[0];
    __syncthreads();
    int base = bid * 1024;
    int idx0 = base + t * 4;
    int c[4]; int tot = 0;
    for (int j = 0; j < 4; ++j) {
        int i = idx0 + j;
        c[j] = (i < N_NODES) ? cnt[i] : 0;
        tot += c[j];
    }
    sd[t] = tot; __syncthreads();
    for (int off = 1; off < 256; off <<= 1) {
        int v = (t >= off) ? sd[t - off] : 0;
        __syncthreads();
        sd[t] += v;
        __syncthreads();
    }
    int excl = sd[t] - tot + s_off;
    for (int j = 0; j < 4; ++j) {
        int i = idx0 + j;
        if (i < N_NODES) {
            row_ptr[i] = excl;
            cursor[i] = excl;
            float dv = rsqrtf((float)(c[j] + 1));   // deg = in-degree + self-loop
            dinv[i] = dv;
            xp[i] = x[i] * dv;
            excl += c[j];
        }
    }
    if (bid == nb - 1 && t == 255) row_ptr[N_NODES] = excl;
}

// XCD-bound windowed fill (pure scatter — fusing layer1's edge-sum here
// regressed: the fp32 atomic re-dirties lines and doubles atomic traffic).
#define FILL_WIN 8
#define FILL_RANGE (N_NODES / FILL_WIN)     // 12500
#define EPR ((N_EDGES + 255) / 256)         // 6250 edges per rank
__global__ void __launch_bounds__(256) k_fill(const int* __restrict__ row,
                                              const int* __restrict__ col,
                                              int* __restrict__ cursor,
                                              int* __restrict__ csr_src) {
    int w = blockIdx.x & 7;
    int rank = blockIdx.x >> 3;             // 0..255
    int lo = w * FILL_RANGE;
    int hi = (w == FILL_WIN - 1) ? N_NODES : lo + FILL_RANGE;
    int e0 = rank * EPR;
    int e1 = min(e0 + EPR, N_EDGES);
    for (int e = e0 + threadIdx.x; e < e1; e += 256) {
        int c = col[e];
        if (c >= lo && c < hi) {
            int pos = atomicAdd(&cursor[c], 1);
            csr_src[pos] = row[e];
        }
    }
}

// ------------- layer 1 (scalar aggregation, 16-wide pipelined) -------------
__global__ void k_layer1(const float* __restrict__ x, const float* __restrict__ xp,
                         const int* __restrict__ batch,
                         const int* __restrict__ row_ptr, const int* __restrict__ csr_src,
                         const float* __restrict__ dinv, float4* __restrict__ node_info) {
    int v = blockIdx.x * blockDim.x + threadIdx.x;
    if (v >= N_NODES) return;
    int e0 = row_ptr[v], e1 = row_ptr[v + 1];
    float acc = 0.f;
    for (int base = e0; base < e1; base += 16) {
        int src[16]; float xv[16];
#pragma unroll
        for (int j = 0; j < 16; ++j) { int e = base + j; src[j] = csr_src[(e < e1) ? e : e0]; }
#pragma unroll
        for (int j = 0; j < 16; ++j) { xv[j] = xp[src[j]]; }
#pragma unroll
        for (int j = 0; j < 16; ++j) { acc += (base + j < e1) ? xv[j] : 0.f; }
    }
    float dv = dinv[v];
    float u = dv * acc + x[v] * dv * dv;    // conv1 scalar output (pre-W1)
    node_info[v] = make_float4(u, dv, __int_as_float((int)batch[v]), 0.f);
}

// ------------- per-graph scalar stats + A/B tables (merged) -------------
__global__ void __launch_bounds__(192) k_stats_ab(const float4* __restrict__ node_info,
                                                  const int* __restrict__ gstart,
                                                  const float* __restrict__ W1, const float* __restrict__ b1,
                                                  const float* __restrict__ g1, const float* __restrict__ be1,
                                                  const float* __restrict__ a1,
                                                  float* __restrict__ A, float* __restrict__ B) {
    __shared__ float sd[192], sd2[192];
    int g = blockIdx.x, t = threadIdx.x;
    int i0 = gstart[g], i1 = gstart[g + 1];
    float s = 0.f, s2 = 0.f;
    for (int i = i0 + t; i < i1; i += 192) { float u = node_info[i].x; s += u; s2 += u * u; }
    sd[t] = s; sd2[t] = s2; __syncthreads();
    for (int off = 96; off >= 3; off >>= 1) {
        if (t < off) { sd[t] += sd[t + off]; sd2[t] += sd2[t + off]; }
        __syncthreads();
    }
    float sum_u = sd[0] + sd[1] + sd[2];
    float sum_u2 = sd2[0] + sd2[1] + sd2[2];
    float cntf = fmaxf((float)(i1 - i0), 1.f);
    float m = sum_u / cntf;
    float es2 = sum_u2 / cntf;
    int f = t;
    float w = W1[f], bb = b1[f], al = a1[f];
    float c2 = bb * (1.f - al);
    float d = al * m;
    float eud2 = es2 - 2.f * d * m + d * d;          // E[(u-d)^2]
    float var = w * w * eud2 + 2.f * w * c2 * (m - d) + c2 * c2;
    float rs = rsqrtf(var + EPSV);
    float gam = g1[f];
    A[g * HID + f] = gam * rs * w;
    B[g * HID + f] = gam * rs * (c2 - w * d) + be1[f];
}

// ------------- X1p[v,f] = fp16( relu(A[gv,f]*u_v + B[gv,f]) * dinv_v ) -------------
__global__ void __launch_bounds__(256) k_x1(const float4* __restrict__ node_info,
                                            const float* __restrict__ A,
                                            const float* __restrict__ B,
                                            _Float16* __restrict__ X1p) {
    int wid = threadIdx.x >> 6;
    int lane = threadIdx.x & 63;
    int v = blockIdx.x * 4 + wid;
    if (v >= N_NODES) return;
    float4 ni = node_info[v];
    float u = ni.x, dv = ni.y;
    int g = __float_as_int(ni.z);
    int c4 = (lane < 48 ? lane : 47) * 4;
    float4 Av = *(const float4*)(A + g * HID + c4);
    float4 Bv = *(const float4*)(B + g * HID + c4);
    f16x4 o;
    o[0] = (_Float16)(fmaxf(fmaf(Av.x, u, Bv.x), 0.f) * dv);
    o[1] = (_Float16)(fmaxf(fmaf(Av.y, u, Bv.y), 0.f) * dv);
    o[2] = (_Float16)(fmaxf(fmaf(Av.z, u, Bv.z), 0.f) * dv);
    o[3] = (_Float16)(fmaxf(fmaf(Av.w, u, Bv.w), 0.f) * dv);
    if (lane < 48) *(f16x4*)(X1p + (size_t)v * HID + c4) = o;
}

// ------------- layer 2 aggregation: aggh[v,:] = fp16( dv * (X1p[v] + sum_nbr X1p[s]) ) ----
#define CH 8
__global__ void __launch_bounds__(256) k_conv2(const _Float16* __restrict__ X1p,
                                               const float* __restrict__ dinv,
                                               const int* __restrict__ row_ptr,
                                               const int* __restrict__ csr_src,
                                               _Float16* __restrict__ aggh) {
    int wid = threadIdx.x >> 6;
    int lane = threadIdx.x & 63;
    int v = blockIdx.x * 4 + wid;
    if (v >= N_NODES) return;
    unsigned c8 = (unsigned)(lane < 48 ? lane : 47) * 8u;
    const char* Xb = (const char*)X1p;
    float dv = dinv[v];
    f16x4 sv = *(const f16x4*)(Xb + (unsigned)v * (HID * 2) + c8);
    float a0 = (float)sv[0], a1 = (float)sv[1], a2 = (float)sv[2], a3 = (float)sv[3];
    int e0 = row_ptr[v], e1 = row_ptr[v + 1];
    for (int b = e0; b < e1; b += CH) {
        unsigned off[CH]; float wgt[CH];
#pragma unroll
        for (int j = 0; j < CH; ++j) {
            int e = b + j;
            off[j] = (unsigned)csr_src[(e < e1) ? e : e0] * (unsigned)(HID * 2) + c8;
            wgt[j] = (e < e1) ? 1.f : 0.f;
        }
        f16x4 rv[CH];
#pragma unroll
        for (int j = 0; j < CH; ++j)
            rv[j] = *(const f16x4*)(Xb + off[j]);
#pragma unroll
        for (int j = 0; j < CH; ++j) {
            a0 = fmaf(wgt[j], (float)rv[j][0], a0);
            a1 = fmaf(wgt[j], (float)rv[j][1], a1);
            a2 = fmaf(wgt[j], (float)rv[j][2], a2);
            a3 = fmaf(wgt[j], (float)rv[j][3], a3);
        }
    }
    if (lane < 48) {
        f16x4 o;
        o[0] = (_Float16)(a0 * dv);
        o[1] = (_Float16)(a1 * dv);
        o[2] = (_Float16)(a2 * dv);
        o[3] = (_Float16)(a3 * dv);
        *(f16x4*)((char*)aggh + (unsigned)v * (HID * 2) + c8) = o;
    }
}

// ------------- MFMA GEMM + fused graphnorm2 stats -------------
#define BM 64
__global__ void __launch_bounds__(256) k_gemm(const _Float16* __restrict__ A,
                                              const _Float16* __restrict__ W,
                                              const float* __restrict__ b2,
                                              const int* __restrict__ batch,
                                              _Float16* __restrict__ H,
                                              float* __restrict__ sums,
                                              float* __restrict__ sumsq) {
    __shared__ _Float16 a_lds[BM * HID];   // 24 KB
    __shared__ int bb[BM];
    int t = threadIdx.x;
    int wid = t >> 6, lane = t & 63;
    int row0 = blockIdx.x * BM;
    if (t < BM) { int gr = row0 + t; bb[t] = (gr < N_NODES) ? batch[gr] : -1; }
    const char* Ablk = (const char*)(A + (size_t)row0 * HID);
#pragma unroll
    for (int it = 0; it < 6; ++it) {
        int bo = (it * 256 + t) * 16;
        int r = bo / 384;
        int swz = bo ^ ((r & 7) << 4);
        *(float4*)((char*)a_lds + swz) = *(const float4*)(Ablk + bo);
    }
    int n0 = wid * 48;
    int bn = n0 + (lane & 15);
    int bk0 = (lane >> 4) << 3;            // k group base (0,8,16,24)
    f16x8 bfr[6][3];
#pragma unroll
    for (int kc = 0; kc < 6; ++kc)
#pragma unroll
        for (int nt = 0; nt < 3; ++nt) {
            const _Float16* src = W + (size_t)(kc * 32 + bk0) * HID + bn + nt * 16;
            f16x8 v;
#pragma unroll
            for (int j = 0; j < 8; ++j) v[j] = src[(size_t)j * HID];
            bfr[kc][nt] = v;
        }
    __syncthreads();
    f32x4 acc[4][3];
#pragma unroll
    for (int mt = 0; mt < 4; ++mt)
#pragma unroll
        for (int nt = 0; nt < 3; ++nt) acc[mt][nt] = (f32x4){0.f, 0.f, 0.f, 0.f};
    int ar = lane & 15;
#pragma unroll
    for (int mt = 0; mt < 4; ++mt) {
        int r = mt * 16 + ar;
        int rbase = r * 384;
        int sw = (r & 7) << 4;
#pragma unroll
        for (int kc = 0; kc < 6; ++kc) {
            int bo = (rbase + (kc * 32 + bk0) * 2) ^ sw;
            f16x8 a = *(const f16x8*)((const char*)a_lds + bo);
            acc[mt][0] = __builtin_amdgcn_mfma_f32_16x16x32_f16(a, bfr[kc][0], acc[mt][0], 0, 0, 0);
            acc[mt][1] = __builtin_amdgcn_mfma_f32_16x16x32_f16(a, bfr[kc][1], acc[mt][1], 0, 0, 0);
            acc[mt][2] = __builtin_amdgcn_mfma_f32_16x16x32_f16(a, bfr[kc][2], acc[mt][2], 0, 0, 0);
        }
    }
    // epilogue: bias + fp16 store + segment stats (D: col=lane&15, row=(lane>>4)*4+reg)
    int cn = lane & 15;
    int rb = (lane >> 4) * 4;
    float bias[3];
#pragma unroll
    for (int nt = 0; nt < 3; ++nt) bias[nt] = b2[n0 + nt * 16 + cn];
    int gA = bb[0];
    int lastv = min(BM, N_NODES - row0) - 1;
    int gB = bb[lastv];
    float sA[3] = {0.f,0.f,0.f}, qA[3] = {0.f,0.f,0.f};
    float sB[3] = {0.f,0.f,0.f}, qB[3] = {0.f,0.f,0.f};
#pragma unroll
    for (int mt = 0; mt < 4; ++mt)
#pragma unroll
        for (int r = 0; r < 4; ++r) {
            int ridx = mt * 16 + rb + r;
            int grow = row0 + ridx;
            if (grow < N_NODES) {
                int gi = bb[ridx];
                _Float16* o = H + (size_t)grow * HID;
#pragma unroll
                for (int nt = 0; nt < 3; ++nt) {
                    float val = acc[mt][nt][r] + bias[nt];
                    o[n0 + nt * 16 + cn] = (_Float16)val;
                    if (gi == gA) { sA[nt] += val; qA[nt] += val * val; }
                    else          { sB[nt] += val; qB[nt] += val * val; }
                }
            }
        }
#pragma unroll
    for (int nt = 0; nt < 3; ++nt) {
        sA[nt] += __shfl_xor(sA[nt], 16); sA[nt] += __shfl_xor(sA[nt], 32);
        qA[nt] += __shfl_xor(qA[nt], 16); qA[nt] += __shfl_xor(qA[nt], 32);
        sB[nt] += __shfl_xor(sB[nt], 16); sB[nt] += __shfl_xor(sB[nt], 32);
        qB[nt] += __shfl_xor(qB[nt], 16); qB[nt] += __shfl_xor(qB[nt], 32);
    }
    if (lane < 16) {
#pragma unroll
        for (int nt = 0; nt < 3; ++nt) {
            int colf = n0 + nt * 16 + cn;
            atomicAdd(&sums[gA * HID + colf], sA[nt]);
            atomicAdd(&sumsq[gA * HID + colf], qA[nt]);
            if (gB != gA) {
                atomicAdd(&sums[gB * HID + colf], sB[nt]);
                atomicAdd(&sumsq[gB * HID + colf], qB[nt]);
            }
        }
    }
}

// ------------- pool: relu(C*h+D) per graph with inline C/D (atomics) -------------
__global__ void __launch_bounds__(192) k_pool(const _Float16* __restrict__ h,
                                              const int* __restrict__ batch,
                                              const int* __restrict__ gstart,
                                              const float* __restrict__ sums,
                                              const float* __restrict__ sumsq,
                                              const float* __restrict__ g2,
                                              const float* __restrict__ be2,
                                              const float* __restrict__ a2,
                                              float* __restrict__ pooled) {
    int f = threadIdx.x;
    int r0 = blockIdx.x * 64;
    int r1 = min(r0 + 64, N_NODES);
    float al = a2[f], gam = g2[f], bet = be2[f];
    int g = batch[r0];
    float Cg, Dg;
    auto cd = [&](int gg) {
        float cntf = fmaxf((float)(gstart[gg + 1] - gstart[gg]), 1.f);
        float mh = sums[gg * HID + f] / cntf;
        float msq = sumsq[gg * HID + f] / cntf;
        float var = msq - 2.f * al * mh * mh + al * al * mh * mh;
        Cg = gam * rsqrtf(var + EPSV);
        Dg = bet - Cg * al * mh;
    };
    cd(g);
    float s = 0.f;
    int i = r0;
    for (; i + 4 <= r1; i += 4) {
        int g0 = batch[i], g3 = batch[i + 3];
        float v0 = (float)h[(size_t)(i + 0) * HID + f];
        float v1 = (float)h[(size_t)(i + 1) * HID + f];
        float v2 = (float)h[(size_t)(i + 2) * HID + f];
        float v3 = (float)h[(size_t)(i + 3) * HID + f];
        if (g0 == g && g3 == g) {
            s += fmaxf(fmaf(Cg, v0, Dg), 0.f) + fmaxf(fmaf(Cg, v1, Dg), 0.f);
            s += fmaxf(fmaf(Cg, v2, Dg), 0.f) + fmaxf(fmaf(Cg, v3, Dg), 0.f);
        } else {
            float vv[4] = {v0, v1, v2, v3};
            for (int j = 0; j < 4; ++j) {
                int gi = batch[i + j];
                if (gi != g) {
                    atomicAdd(&pooled[g * HID + f], s);
                    s = 0.f; g = gi; cd(g);
                }
                s += fmaxf(fmaf(Cg, vv[j], Dg), 0.f);
            }
        }
    }
    for (; i < r1; ++i) {
        int gi = batch[i];
        float v = (float)h[(size_t)i * HID + f];
        if (gi != g) {
            atomicAdd(&pooled[g * HID + f], s);
            s = 0.f; g = gi; cd(g);
        }
        s += fmaxf(fmaf(Cg, v, Dg), 0.f);
    }
    atomicAdd(&pooled[g * HID + f], s);
}

// ------------- final MLP: out = relu((pooled/cnt)@Wc1+bc1)@Wc2 + bc2 -------------
__global__ void __launch_bounds__(128) k_mlp(const float* __restrict__ pooled,
                                             const int* __restrict__ gstart,
                                             const float* __restrict__ Wc1,
                                             const float* __restrict__ bc1,
                                             const float* __restrict__ Wc2,
                                             const float* __restrict__ bc2,
                                             float* __restrict__ out) {
    __shared__ float p[HID];
    __shared__ float z[96];
    int g = blockIdx.x, t = threadIdx.x;
    float inv = 1.f / fmaxf((float)(gstart[g + 1] - gstart[g]), 1.f);
    for (int i = t; i < HID; i += 128) p[i] = pooled[g * HID + i] * inv;
    __syncthreads();
    if (t < 96) {
        float acc = bc1[t];
        for (int k = 0; k < HID; ++k) acc += p[k] * Wc1[k * 96 + t];
        z[t] = fmaxf(acc, 0.f);
    }
    __syncthreads();
    if (t < 4) {
        float acc = bc2[t];
        for (int j = 0; j < 96; ++j) acc += z[j] * Wc2[j * 4 + t];
        out[g * 4 + t] = acc;
    }
}

extern "C" void kernel_launch(void* const* d_in, const int* in_sizes, int n_in,
                              void* d_out, int out_size, void* d_ws, size_t ws_size,
                              hipStream_t stream) {
    const float* x   = (const float*)d_in[0];
    const int* eidx  = (const int*)d_in[1];
    const int* batch = (const int*)d_in[2];
    const float* W1  = (const float*)d_in[3];
    const float* b1  = (const float*)d_in[4];
    const float* g1  = (const float*)d_in[5];
    const float* be1 = (const float*)d_in[6];
    const float* a1  = (const float*)d_in[7];
    const float* W2  = (const float*)d_in[8];
    const float* b2  = (const float*)d_in[9];
    const float* g2  = (const float*)d_in[10];
    const float* be2 = (const float*)d_in[11];
    const float* a2  = (const float*)d_in[12];
    const float* Wc1 = (const float*)d_in[13];
    const float* bc1 = (const float*)d_in[14];
    const float* Wc2 = (const float*)d_in[15];
    const float* bc2 = (const float*)d_in[16];
    const int* row = eidx;
    const int* col = eidx + N_EDGES;
    float* out = (float*)d_out;

    char* ws = (char*)d_ws;
    size_t off = 0;
    auto alloc = [&](size_t bytes) -> char* {
        char* p = ws + off;
        off = (off + bytes + 255) & ~(size_t)255;
        return p;
    };
    // ---- zero region (contiguous) ----
    int*   cnt     = (int*)  alloc(N_NODES * 4);
    float* sums2   = (float*)alloc(N_GRAPHS * HID * 4);
    float* sumsq2  = (float*)alloc(N_GRAPHS * HID * 4);
    float* pooled  = (float*)alloc(N_GRAPHS * HID * 4);
    size_t zbytes  = off;
    // ---- rest ----
    int*   bsum    = (int*)  alloc(128 * 4);
    int*   row_ptr = (int*)  alloc((N_NODES + 1) * 4);
    int*   cursor  = (int*)  alloc(N_NODES * 4);
    int*   csr_src = (int*)  alloc(N_EDGES * 4);
    float* dinv    = (float*)alloc(N_NODES * 4);
    float* xp      = (float*)alloc(N_NODES * 4);
    float4* node_info = (float4*)alloc((size_t)N_NODES * 16);
    float* Atab    = (float*)alloc(N_GRAPHS * HID * 4);
    float* Btab    = (float*)alloc(N_GRAPHS * HID * 4);
    int*   gstart  = (int*)  alloc((N_GRAPHS + 1) * 4);
    _Float16* X1p  = (_Float16*)alloc((size_t)N_NODES * HID * 2);
    _Float16* aggh = (_Float16*)alloc((size_t)N_PAD * HID * 2);
    _Float16* h2   = (_Float16*)alloc((size_t)N_NODES * HID * 2);
    _Float16* W2h  = (_Float16*)alloc((size_t)HID * HID * 2);

    hipMemsetAsync(ws, 0, zbytes, stream);
    k_misc<<<(HID * HID + N_GRAPHS + 1 + 255) / 256, 256, 0, stream>>>(W2, W2h, batch, gstart);
    k_count<<<(N_EDGES + 255) / 256, 256, 0, stream>>>(col, cnt);
    int PB = (N_NODES + 1023) / 1024;
    k_scan_partial<<<PB, 256, 0, stream>>>(cnt, bsum);
    k_scan_final<<<PB, 256, 0, stream>>>(cnt, bsum, PB, row_ptr, cursor, dinv, x, xp);
    k_fill<<<2048, 256, 0, stream>>>(row, col, cursor, csr_src);
    k_layer1<<<(N_NODES + 255) / 256, 256, 0, stream>>>(x, xp, batch, row_ptr, csr_src, dinv, node_info);
    k_stats_ab<<<N_GRAPHS, 192, 0, stream>>>(node_info, gstart, W1, b1, g1, be1, a1, Atab, Btab);
    k_x1<<<(N_NODES + 3) / 4, 256, 0, stream>>>(node_info, Atab, Btab, X1p);
    k_conv2<<<(N_NODES + 3) / 4, 256, 0, stream>>>(X1p, dinv, row_ptr, csr_src, aggh);
    k_gemm<<<(N_NODES + BM - 1) / BM, 256, 0, stream>>>(aggh, W2h, b2, batch, h2, sums2, sumsq2);
    int SB = (N_NODES + 63) / 64;
    k_pool<<<SB, 192, 0, stream>>>(h2, batch, gstart, sums2, sumsq2, g2, be2, a2, pooled);
    k_mlp<<<N_GRAPHS, 128, 0, stream>>>(pooled, gstart, Wc1, bc1, Wc2, bc2, out);
}